// Round 22
// baseline (90.113 us; speedup 1.0000x reference)
//
#include <hip/hip_runtime.h>
#include <hip/hip_bf16.h>
#include <hip/hip_fp16.h>

#define BB 4
#define CC_ 384
#define HH 32
#define WW 32
#define HWSZ 1024
#define NHD 12
#define HCH 32
#define GG 6
#define NGC_ 64
#define GHD 2
#define HK_ 16
#define WK_ 16
#define NS_ 256
#define RPEW 63
#define SCALE_ 0.17677669529663687f

typedef _Float16 half8_t __attribute__((ext_vector_type(8)));
typedef float f32x4_t __attribute__((ext_vector_type(4)));
typedef unsigned u32x4_t __attribute__((ext_vector_type(4)));

// ---------------- prep: 4x weight cvt + x transpose in ONE launch ----------------
__global__ __launch_bounds__(256)
void prep_kernel(const float* __restrict__ w0, const float* __restrict__ w1,
                 const float* __restrict__ w2, const float* __restrict__ w3,
                 __half* __restrict__ o0, __half* __restrict__ o1,
                 __half* __restrict__ o2, __half* __restrict__ o3,
                 const float* __restrict__ X, __half* __restrict__ XT)
{
    __shared__ float tile[64][65];
    const int bid = blockIdx.x;
    const int tid = threadIdx.x;
    if (bid < 576) {
        const int m = bid / 144;
        const float* src = (m == 0) ? w0 : (m == 1) ? w1 : (m == 2) ? w2 : w3;
        __half* dst = (m == 0) ? o0 : (m == 1) ? o1 : (m == 2) ? o2 : o3;
        int i = (bid - m * 144) * 256 + tid;
        if (i < CC_ * CC_ / 4) {
            float4 v = *(const float4*)(src + (size_t)i * 4);
            __half2* d = (__half2*)(dst + (size_t)i * 4);
            d[0] = __floats2half2_rn(v.x, v.y);
            d[1] = __floats2half2_rn(v.z, v.w);
        }
    } else {
        const int t = bid - 576;
        const int n0 = (t & 15) * 64;
        const int c0 = ((t >> 4) % 6) * 64;
        const int b = t / 96;
        const int tn = tid & 63, tg = tid >> 6;
#pragma unroll
        for (int k = 0; k < 16; ++k) {
            int r = k * 4 + tg;
            tile[r][tn] = X[((size_t)(b * CC_ + c0 + r)) * HWSZ + n0 + tn];
        }
        __syncthreads();
        const int cp = tg * 16;
        __half hb[16] __attribute__((aligned(16)));
#pragma unroll
        for (int j = 0; j < 16; ++j) hb[j] = __float2half(tile[cp + j][tn]);
        __half* dst = XT + ((size_t)(b * HWSZ + n0 + tn)) * CC_ + c0 + cp;
        *(uint4*)(dst) = *(uint4*)(hb);
        *(uint4*)(dst + 8) = *(uint4*)(hb + 8);
    }
}

// ---------------- K6: MFMA fp16 conv1x1 (fp32 out), BN=16 for 6 waves/SIMD ----------------
// grid: (N/16, OC/64, B), block 256 = 4 waves on o.
template<int CIN>
__global__ __launch_bounds__(256)
void conv1x1_mfma_h(const __half* __restrict__ Wh, const float* __restrict__ bias,
                    const __half* __restrict__ XT, float* __restrict__ Y, int N, int OC)
{
    const int tid = threadIdx.x;
    const int wv = tid >> 6;
    const int lane = tid & 63;
    const int l15 = lane & 15, lhi = lane >> 4;
    const int otile = blockIdx.y * 64 + wv * 16;
    const int ntile = blockIdx.x * 16;
    const int b = blockIdx.z;

    const __half* Wp = Wh + (size_t)(otile + l15) * CIN + lhi * 8;
    const __half* Xp0 = XT + ((size_t)(b * N + ntile + l15)) * CIN + lhi * 8;

    f32x4_t acc0 = {0.f, 0.f, 0.f, 0.f};
#pragma unroll
    for (int k0 = 0; k0 < CIN; k0 += 32) {
        half8_t af = *(const half8_t*)(Wp + k0);
        half8_t b0 = *(const half8_t*)(Xp0 + k0);
        acc0 = __builtin_amdgcn_mfma_f32_16x16x32_f16(af, b0, acc0, 0, 0, 0);
    }
#pragma unroll
    for (int r = 0; r < 4; ++r) {
        float bv = bias[otile + lhi * 4 + r];
        Y[((size_t)(b * OC + otile + lhi * 4 + r)) * N + ntile + l15] = acc0[r] + bv;
    }
}

// ---------------- K1: MFMA conv for q (BN=16): fp32 [b][c][n] + fp16 SCALED [b][n][c] ----------------
__global__ __launch_bounds__(256)
void convq_mfma(const __half* __restrict__ Wh, const float* __restrict__ bias,
                const __half* __restrict__ XT, float* __restrict__ Y,
                __half* __restrict__ Qh)
{
    const int tid = threadIdx.x;
    const int wv = tid >> 6;
    const int lane = tid & 63;
    const int l15 = lane & 15, lhi = lane >> 4;
    const int otile = blockIdx.y * 64 + wv * 16;
    const int ntile = blockIdx.x * 16;
    const int b = blockIdx.z;

    const __half* Wp = Wh + (size_t)(otile + l15) * CC_ + lhi * 8;
    const __half* Xp0 = XT + ((size_t)(b * HWSZ + ntile + l15)) * CC_ + lhi * 8;

    f32x4_t acc0 = {0.f, 0.f, 0.f, 0.f};
#pragma unroll
    for (int k0 = 0; k0 < CC_; k0 += 32) {
        half8_t af = *(const half8_t*)(Wp + k0);
        half8_t b0 = *(const half8_t*)(Xp0 + k0);
        acc0 = __builtin_amdgcn_mfma_f32_16x16x32_f16(af, b0, acc0, 0, 0, 0);
    }
    float bv[4];
#pragma unroll
    for (int r = 0; r < 4; ++r) bv[r] = bias[otile + lhi * 4 + r];
#pragma unroll
    for (int r = 0; r < 4; ++r)
        Y[((size_t)(b * CC_ + otile + lhi * 4 + r)) * HWSZ + ntile + l15] = acc0[r] + bv[r];
    {
        int n0 = ntile + l15;
        __half2 h0 = __floats2half2_rn((acc0[0] + bv[0]) * SCALE_, (acc0[1] + bv[1]) * SCALE_);
        __half2 h1 = __floats2half2_rn((acc0[2] + bv[2]) * SCALE_, (acc0[3] + bv[3]) * SCALE_);
        uint2 u;
        u.x = __builtin_bit_cast(unsigned, h0);
        u.y = __builtin_bit_cast(unsigned, h1);
        *(uint2*)(Qh + ((size_t)(b * HWSZ + n0)) * CC_ + otile + lhi * 4) = u;
    }
}

// ---------------- K4: MFMA fused K+V conv; K fp16 [bh][s][32], V fp16 [bh][c][s] ----------------
template<int CIN>
__global__ __launch_bounds__(256)
void convkv_mfma(const __half* __restrict__ Wkh, const float* __restrict__ bk,
                 const __half* __restrict__ Wvh, const float* __restrict__ bv,
                 const __half* __restrict__ XS, __half* __restrict__ Yk,
                 __half* __restrict__ Yv)
{
    const int tid = threadIdx.x;
    const int wv = tid >> 6;
    const int lane = tid & 63;
    const int l15 = lane & 15, lhi = lane >> 4;
    const int otile = blockIdx.y * 64 + wv * 16;
    const int stile = blockIdx.x * 32;
    const int b = blockIdx.z;

    const __half* Wkp = Wkh + (size_t)(otile + l15) * CIN + lhi * 8;
    const __half* Wvp = Wvh + (size_t)(otile + l15) * CIN + lhi * 8;
    const __half* Xp0 = XS + ((size_t)(b * NS_ + stile + l15)) * CIN + lhi * 8;
    const __half* Xp1 = Xp0 + (size_t)16 * CIN;

    f32x4_t ka0 = {0.f,0.f,0.f,0.f}, ka1 = {0.f,0.f,0.f,0.f};
    f32x4_t va0 = {0.f,0.f,0.f,0.f}, va1 = {0.f,0.f,0.f,0.f};
#pragma unroll
    for (int c0 = 0; c0 < CIN; c0 += 32) {
        half8_t ak = *(const half8_t*)(Wkp + c0);
        half8_t av = *(const half8_t*)(Wvp + c0);
        half8_t b0 = *(const half8_t*)(Xp0 + c0);
        half8_t b1 = *(const half8_t*)(Xp1 + c0);
        ka0 = __builtin_amdgcn_mfma_f32_16x16x32_f16(ak, b0, ka0, 0, 0, 0);
        ka1 = __builtin_amdgcn_mfma_f32_16x16x32_f16(ak, b1, ka1, 0, 0, 0);
        va0 = __builtin_amdgcn_mfma_f32_16x16x32_f16(av, b0, va0, 0, 0, 0);
        va1 = __builtin_amdgcn_mfma_f32_16x16x32_f16(av, b1, va1, 0, 0, 0);
    }
    const int h = otile >> 5;
    const int c32 = (otile & 31) + lhi * 4;
    const size_t bh = (size_t)(b * NHD + h);
    float bkv[4], bvv[4];
#pragma unroll
    for (int r = 0; r < 4; ++r) {
        bkv[r] = bk[otile + lhi * 4 + r];
        bvv[r] = bv[otile + lhi * 4 + r];
    }
    {
        size_t base = (bh * NS_ + stile + l15) * 32 + c32;
        __half2 kh[2];
        kh[0] = __floats2half2_rn(ka0[0] + bkv[0], ka0[1] + bkv[1]);
        kh[1] = __floats2half2_rn(ka0[2] + bkv[2], ka0[3] + bkv[3]);
        *(uint2*)(Yk + base) = *(uint2*)kh;
        base = (bh * NS_ + stile + 16 + l15) * 32 + c32;
        kh[0] = __floats2half2_rn(ka1[0] + bkv[0], ka1[1] + bkv[1]);
        kh[1] = __floats2half2_rn(ka1[2] + bkv[2], ka1[3] + bkv[3]);
        *(uint2*)(Yk + base) = *(uint2*)kh;
    }
    {
        __half* vdst = Yv + (bh * 32 + c32) * NS_;
#pragma unroll
        for (int r = 0; r < 4; ++r) {
            vdst[(size_t)r * NS_ + stile + l15]      = __float2half(va0[r] + bvv[r]);
            vdst[(size_t)r * NS_ + stile + 16 + l15] = __float2half(va1[r] + bvv[r]);
        }
    }
}

// ---------------- K2a: depthwise conv 5x5 stride 2, transposed output [bg][pos][ch] ----------------
__global__ void offset_dw_kernel(const float* __restrict__ qb, const float* __restrict__ dww,
                                 const float* __restrict__ dwb, float* __restrict__ cobuf)
{
    __shared__ float img[HWSZ];
    const int c = blockIdx.x, bg = blockIdx.y;
    const int b = bg / GG, g = bg - b * GG;
    const int tid = threadIdx.x;
    const float* src = qb + ((size_t)(b * CC_ + g * NGC_ + c)) * HWSZ;
    ((float4*)img)[tid] = ((const float4*)src)[tid];
    __syncthreads();
    const int oy = tid >> 4, ox = tid & 15;
    float s = dwb[c];
    const float* wf = dww + c * 25;
    const int iy0 = oy * 2 - 2, ix0 = ox * 2 - 2;
#pragma unroll
    for (int ky = 0; ky < 5; ++ky) {
        int iy = iy0 + ky;
        if (iy < 0 || iy > 31) continue;
#pragma unroll
        for (int kx = 0; kx < 5; ++kx) {
            int ix = ix0 + kx;
            if (ix < 0 || ix > 31) continue;
            s = fmaf(img[iy * 32 + ix], wf[ky * 5 + kx], s);
        }
    }
    cobuf[((size_t)(bg * 256 + tid)) * NGC_ + c] = s;
}

// ---------------- K2b+K3 fused: LN+GELU+pw+tanh -> pos, bilinear sample of xh -> xsh ----------------
__global__ void offset_finsample_kernel(const float* __restrict__ cobuf, const float* __restrict__ lng,
                                        const float* __restrict__ lnb, const float* __restrict__ pww,
                                        const __half* __restrict__ xh, float* __restrict__ posb,
                                        __half* __restrict__ xsh)
{
    __shared__ float pos_s[8];
    const int lane = threadIdx.x & 63;
    const int wv = threadIdx.x >> 6;
    const int gpos = blockIdx.x * 4 + wv;
    const int bg = gpos >> 8, pos = gpos & 255;
    const int oy = (pos >> 4), ox = pos & 15;
    const int b = bg / GG, g = bg - b * GG;

    float v = cobuf[(size_t)gpos * NGC_ + lane];
    float s1 = v, s2 = v * v;
#pragma unroll
    for (int off = 32; off >= 1; off >>= 1) {
        s1 += __shfl_xor(s1, off);
        s2 += __shfl_xor(s2, off);
    }
    float mu = s1 * (1.f / 64.f);
    float var = s2 * (1.f / 64.f) - mu * mu;
    float rstd = rsqrtf(var + 1e-5f);
    float t = (v - mu) * rstd * lng[lane] + lnb[lane];
    float gv = 0.5f * t * (1.f + erff(t * 0.70710678118654752f));
    float o0 = pww[lane] * gv;
    float o1 = pww[64 + lane] * gv;
#pragma unroll
    for (int off = 32; off >= 1; off >>= 1) {
        o0 += __shfl_xor(o0, off);
        o1 += __shfl_xor(o1, off);
    }
    if (lane == 0) {
        float py = tanhf(o0) * (2.f / 15.f) + ((0.5f + (float)oy) * (1.f / 15.f)) * 2.f - 1.f;
        float px = tanhf(o1) * (2.f / 15.f) + ((0.5f + (float)ox) * (1.f / 15.f)) * 2.f - 1.f;
        posb[bg * 512 + pos * 2 + 0] = py;
        posb[bg * 512 + pos * 2 + 1] = px;
        pos_s[wv * 2 + 0] = py;
        pos_s[wv * 2 + 1] = px;
    }
    __syncthreads();

    float py = pos_s[wv * 2 + 0], px = pos_s[wv * 2 + 1];
    float xi = (px + 1.f) * 0.5f * 31.f;
    float yi = (py + 1.f) * 0.5f * 31.f;
    float x0f = floorf(xi), y0f = floorf(yi);
    int x0 = (int)x0f, y0 = (int)y0f;
    float wx1 = xi - x0f, wy1 = yi - y0f;
    const __half* imgc = xh + (size_t)(b * HWSZ) * CC_ + g * NGC_ + lane;
    float acc = 0.f;
#pragma unroll
    for (int tt = 0; tt < 4; ++tt) {
        int iy = y0 + (tt >> 1), ix = x0 + (tt & 1);
        float w = ((tt >> 1) ? wy1 : 1.f - wy1) * ((tt & 1) ? wx1 : 1.f - wx1);
        if (iy >= 0 && iy <= 31 && ix >= 0 && ix <= 31)
            acc = fmaf(__half2float(imgc[(size_t)(iy * 32 + ix) * CC_]), w, acc);
    }
    xsh[((size_t)(b * NS_ + pos)) * CC_ + g * NGC_ + lane] = __float2half(acc);
}

// ---------------- K5: full-MFMA attention, 8 waves / 128 q per block ----------------
__launch_bounds__(512)
__global__ void attn_mfma(const __half* __restrict__ qh, const __half* __restrict__ kt,
                          const __half* __restrict__ vt, const float* __restrict__ posb,
                          const float* __restrict__ rpe, __half* __restrict__ aoT)
{
    __shared__ __half rph[4096];
    __shared__ float4 ytab[1024];
    const int bh = blockIdx.y;
    const int b = bh / NHD, h = bh - b * NHD;
    const int bg = b * GG + (h >> 1);
    const int tid = threadIdx.x;
    for (int e = tid; e < RPEW * RPEW; e += 512)
        rph[e] = __float2half(rpe[(size_t)h * (RPEW * RPEW) + e]);
    const int base_row = blockIdx.x * 4;
    for (int e = tid; e < 1024; e += 512) {
        int rr = e >> 8, s = e & 255;
        float py = posb[bg * 512 + s * 2 + 0];
        float px = posb[bg * 512 + s * 2 + 1];
        float ycr = ((float)(base_row + rr) * (2.f / 31.f) - 1.f) * 15.5f + 31.f;
        float yi = fmaf(py, -15.5f, ycr);
        float y0f = floorf(yi);
        int iy = (int)y0f;
        float wy1 = yi - y0f, wy0 = 1.f - wy1;
        if ((unsigned)iy > 62u)       wy0 = 0.f;
        if ((unsigned)(iy + 1) > 62u) wy1 = 0.f;
        int ry0 = min(max(iy, 0), 62) * 63;
        int ry1 = min(max(iy + 1, 0), 62) * 63;
        float4 t;
        t.x = __int_as_float(ry0);
        t.y = __int_as_float(ry1);
        t.z = __uint_as_float(__builtin_bit_cast(unsigned, __floats2half2_rn(wy0, wy1)));
        t.w = px * 15.5f;
        ytab[rr * 256 + s] = t;
    }
    __syncthreads();

    const int wave = tid >> 6;
    const int lane = tid & 63;
    const int l15 = lane & 15, lhi = lane >> 4;
    const int qglob = blockIdx.x * 128 + wave * 16 + l15;
    const int col = qglob & 31;
    const float xc = ((float)col * (2.f / 31.f) - 1.f) * 15.5f + 31.f;
    const int rowl = wave >> 1;

    half8_t qf = *(const half8_t*)(qh + ((size_t)(b * HWSZ + qglob)) * CC_ + h * HCH + lhi * 8);

    const __half* kbase = kt + (size_t)bh * NS_ * 32;
    const __half* vbase = vt + (size_t)bh * 32 * NS_;

    f32x4_t oacc0 = {0.f,0.f,0.f,0.f}, oacc1 = {0.f,0.f,0.f,0.f};
    const f32x4_t zero4 = {0.f,0.f,0.f,0.f};
    float lsum = 0.f;

    for (int chunk = 0; chunk < 8; ++chunk) {
        const int sbase = chunk * 32;
        unsigned wa0 = 0, wa1 = 0, wb0 = 0, wb1 = 0;
#pragma unroll
        for (int t = 0; t < 2; ++t) {
            const int stile = sbase + t * 16;
            half8_t kf = *(const half8_t*)(kbase + (size_t)(stile + l15) * 32 + lhi * 8);
            f32x4_t sf = __builtin_amdgcn_mfma_f32_16x16x32_f16(kf, qf, zero4, 0, 0, 0);
            float pv[4];
#pragma unroll
            for (int r = 0; r < 4; ++r) {
                const int s = stile + lhi * 4 + r;
                float4 yt = ytab[rowl * 256 + s];
                int ry0 = __float_as_int(yt.x), ry1 = __float_as_int(yt.y);
                __half2 wyh = __builtin_bit_cast(__half2, __float_as_uint(yt.z));
                float wy0 = __low2float(wyh), wy1 = __high2float(wyh);
                float xi = xc - yt.w;
                float x0f = floorf(xi);
                int ix = (int)x0f;
                float wx1 = xi - x0f, wx0 = 1.f - wx1;
                if ((unsigned)ix > 62u)       wx0 = 0.f;
                if ((unsigned)(ix + 1) > 62u) wx1 = 0.f;
                int cx0 = min(max(ix, 0), 62);
                int cx1 = min(max(ix + 1, 0), 62);
                float t00 = __half2float(rph[ry0 + cx0]), t01 = __half2float(rph[ry0 + cx1]);
                float t10 = __half2float(rph[ry1 + cx0]), t11 = __half2float(rph[ry1 + cx1]);
                float bias = wy0 * fmaf(wx0, t00, wx1 * t01)
                           + wy1 * fmaf(wx0, t10, wx1 * t11);
                float p = __expf(sf[r] + bias);
                lsum += p;
                pv[r] = p;
            }
            unsigned w0 = __builtin_bit_cast(unsigned, __floats2half2_rn(pv[0], pv[1]));
            unsigned w1 = __builtin_bit_cast(unsigned, __floats2half2_rn(pv[2], pv[3]));
            if (t == 0) { wa0 = w0; wa1 = w1; } else { wb0 = w0; wb1 = w1; }
        }
        const int srcA = l15 + ((lhi & 1) << 5);
        const int srcB = srcA + 16;
        int g0a = __shfl((int)wa0, srcA), g0b = __shfl((int)wb0, srcA);
        int g1a = __shfl((int)wa1, srcA), g1b = __shfl((int)wb1, srcA);
        int g2a = __shfl((int)wa0, srcB), g2b = __shfl((int)wb0, srcB);
        int g3a = __shfl((int)wa1, srcB), g3b = __shfl((int)wb1, srcB);
        const bool hi = (lhi >= 2);
        u32x4_t bw;
        bw[0] = (unsigned)(hi ? g0b : g0a);
        bw[1] = (unsigned)(hi ? g1b : g1a);
        bw[2] = (unsigned)(hi ? g2b : g2a);
        bw[3] = (unsigned)(hi ? g3b : g3a);
        half8_t pf = __builtin_bit_cast(half8_t, bw);
        half8_t vf0 = *(const half8_t*)(vbase + (size_t)(l15) * NS_ + sbase + lhi * 8);
        half8_t vf1 = *(const half8_t*)(vbase + (size_t)(16 + l15) * NS_ + sbase + lhi * 8);
        oacc0 = __builtin_amdgcn_mfma_f32_16x16x32_f16(vf0, pf, oacc0, 0, 0, 0);
        oacc1 = __builtin_amdgcn_mfma_f32_16x16x32_f16(vf1, pf, oacc1, 0, 0, 0);
    }
    lsum += __shfl_xor(lsum, 16);
    lsum += __shfl_xor(lsum, 32);
    const float inv = 1.f / lsum;
    __half* og = aoT + ((size_t)(b * HWSZ + qglob)) * CC_ + h * HCH;
    {
        __half2 h0 = __floats2half2_rn(oacc0[0] * inv, oacc0[1] * inv);
        __half2 h1 = __floats2half2_rn(oacc0[2] * inv, oacc0[3] * inv);
        uint2 u;
        u.x = __builtin_bit_cast(unsigned, h0);
        u.y = __builtin_bit_cast(unsigned, h1);
        *(uint2*)(og + lhi * 4) = u;
        h0 = __floats2half2_rn(oacc1[0] * inv, oacc1[1] * inv);
        h1 = __floats2half2_rn(oacc1[2] * inv, oacc1[3] * inv);
        u.x = __builtin_bit_cast(unsigned, h0);
        u.y = __builtin_bit_cast(unsigned, h1);
        *(uint2*)(og + 16 + lhi * 4) = u;
    }
}

extern "C" void kernel_launch(void* const* d_in, const int* in_sizes, int n_in,
                              void* d_out, int out_size, void* d_ws, size_t ws_size,
                              hipStream_t stream) {
    (void)in_sizes; (void)n_in; (void)out_size; (void)ws_size;
    const float* x   = (const float*)d_in[0];
    const float* Wq  = (const float*)d_in[1];
    const float* bq  = (const float*)d_in[2];
    const float* Wk  = (const float*)d_in[3];
    const float* bk  = (const float*)d_in[4];
    const float* Wv  = (const float*)d_in[5];
    const float* bv  = (const float*)d_in[6];
    const float* Wo  = (const float*)d_in[7];
    const float* bo  = (const float*)d_in[8];
    const float* dww = (const float*)d_in[9];
    const float* dwb = (const float*)d_in[10];
    const float* lng = (const float*)d_in[11];
    const float* lnb = (const float*)d_in[12];
    const float* pww = (const float*)d_in[13];
    const float* rpe = (const float*)d_in[14];
    float* out = (float*)d_out;

    // Workspace (float slots). Aliasing audited (R20-validated layout):
    //  cobuf aliases ktb+vth (dw -> finsample -> convkv overwrite, ordering-safe)
    //  qh == aoT alias (attn reads/writes same per-block region)
    float* p = (float*)d_ws;
    float* qbuf  = p; p += 1572864;                 // fp32 [b][c][n]
    float* posb  = p; p += 12288;
    __half* ktb  = (__half*)p; p += 196608;         // K fp16 [bh][s][32]
    __half* vth  = (__half*)p; p += 196608;         // V fp16 [bh][c][s]
    float* cobuf = (float*)ktb;
    __half* xh   = (__half*)p; p += 786432;         // fp16 [b][n][c]
    __half* qh   = (__half*)p; p += 786432;         // fp16 scaled [b][n][c]
    __half* aoT  = qh;
    __half* wqh  = (__half*)p; p += 73728;
    __half* woh  = (__half*)p; p += 73728;
    __half* wkh  = (__half*)p; p += 73728;
    __half* wvh  = (__half*)p; p += 73728;
    __half* xsh  = (__half*)p; p += 196608;         // fp16 [b][s][c]

    prep_kernel<<<dim3(960), 256, 0, stream>>>(Wq, Wo, Wk, Wv, wqh, woh, wkh, wvh, x, xh);
    convq_mfma<<<dim3(HWSZ / 16, CC_ / 64, BB), 256, 0, stream>>>(wqh, bq, xh, qbuf, qh);
    offset_dw_kernel<<<dim3(NGC_, 24), 256, 0, stream>>>(qbuf, dww, dwb, cobuf);
    offset_finsample_kernel<<<dim3(1536), 256, 0, stream>>>(cobuf, lng, lnb, pww, xh, posb, xsh);
    convkv_mfma<CC_><<<dim3(NS_ / 32, CC_ / 64, BB), 256, 0, stream>>>(wkh, bk, wvh, bv, xsh, ktb, vth);
    attn_mfma<<<dim3(8, BB * NHD), 512, 0, stream>>>(qh, ktb, vth, posb, rpe, aoT);
    conv1x1_mfma_h<CC_><<<dim3(HWSZ / 16, CC_ / 64, BB), 256, 0, stream>>>(woh, bo, aoT, out, HWSZ, CC_);
}

// Round 23
// 82.817 us; speedup vs baseline: 1.0881x; 1.0881x over previous
//
#include <hip/hip_runtime.h>
#include <hip/hip_bf16.h>
#include <hip/hip_fp16.h>

#define BB 4
#define CC_ 384
#define HH 32
#define WW 32
#define HWSZ 1024
#define NHD 12
#define HCH 32
#define GG 6
#define NGC_ 64
#define GHD 2
#define HK_ 16
#define WK_ 16
#define NS_ 256
#define RPEW 63
#define SCALE_ 0.17677669529663687f

typedef _Float16 half8_t __attribute__((ext_vector_type(8)));
typedef float f32x4_t __attribute__((ext_vector_type(4)));
typedef unsigned u32x4_t __attribute__((ext_vector_type(4)));

// ---------------- prep: 4x weight cvt + x transpose in ONE launch ----------------
__global__ __launch_bounds__(256)
void prep_kernel(const float* __restrict__ w0, const float* __restrict__ w1,
                 const float* __restrict__ w2, const float* __restrict__ w3,
                 __half* __restrict__ o0, __half* __restrict__ o1,
                 __half* __restrict__ o2, __half* __restrict__ o3,
                 const float* __restrict__ X, __half* __restrict__ XT)
{
    __shared__ float tile[64][65];
    const int bid = blockIdx.x;
    const int tid = threadIdx.x;
    if (bid < 576) {
        const int m = bid / 144;
        const float* src = (m == 0) ? w0 : (m == 1) ? w1 : (m == 2) ? w2 : w3;
        __half* dst = (m == 0) ? o0 : (m == 1) ? o1 : (m == 2) ? o2 : o3;
        int i = (bid - m * 144) * 256 + tid;
        if (i < CC_ * CC_ / 4) {
            float4 v = *(const float4*)(src + (size_t)i * 4);
            __half2* d = (__half2*)(dst + (size_t)i * 4);
            d[0] = __floats2half2_rn(v.x, v.y);
            d[1] = __floats2half2_rn(v.z, v.w);
        }
    } else {
        const int t = bid - 576;
        const int n0 = (t & 15) * 64;
        const int c0 = ((t >> 4) % 6) * 64;
        const int b = t / 96;
        const int tn = tid & 63, tg = tid >> 6;
#pragma unroll
        for (int k = 0; k < 16; ++k) {
            int r = k * 4 + tg;
            tile[r][tn] = X[((size_t)(b * CC_ + c0 + r)) * HWSZ + n0 + tn];
        }
        __syncthreads();
        const int cp = tg * 16;
        __half hb[16] __attribute__((aligned(16)));
#pragma unroll
        for (int j = 0; j < 16; ++j) hb[j] = __float2half(tile[cp + j][tn]);
        __half* dst = XT + ((size_t)(b * HWSZ + n0 + tn)) * CC_ + c0 + cp;
        *(uint4*)(dst) = *(uint4*)(hb);
        *(uint4*)(dst + 8) = *(uint4*)(hb + 8);
    }
}

// ---------------- K6: MFMA fp16 conv1x1 (fp32 out), BN=32 ----------------
template<int CIN>
__global__ __launch_bounds__(256)
void conv1x1_mfma_h(const __half* __restrict__ Wh, const float* __restrict__ bias,
                    const __half* __restrict__ XT, float* __restrict__ Y, int N, int OC)
{
    const int tid = threadIdx.x;
    const int wv = tid >> 6;
    const int lane = tid & 63;
    const int l15 = lane & 15, lhi = lane >> 4;
    const int otile = blockIdx.y * 64 + wv * 16;
    const int ntile = blockIdx.x * 32;
    const int b = blockIdx.z;

    const __half* Wp = Wh + (size_t)(otile + l15) * CIN + lhi * 8;
    const __half* Xp0 = XT + ((size_t)(b * N + ntile + l15)) * CIN + lhi * 8;
    const __half* Xp1 = Xp0 + (size_t)16 * CIN;

    f32x4_t acc0 = {0.f, 0.f, 0.f, 0.f}, acc1 = {0.f, 0.f, 0.f, 0.f};
#pragma unroll
    for (int k0 = 0; k0 < CIN; k0 += 32) {
        half8_t af = *(const half8_t*)(Wp + k0);
        half8_t b0 = *(const half8_t*)(Xp0 + k0);
        half8_t b1 = *(const half8_t*)(Xp1 + k0);
        acc0 = __builtin_amdgcn_mfma_f32_16x16x32_f16(af, b0, acc0, 0, 0, 0);
        acc1 = __builtin_amdgcn_mfma_f32_16x16x32_f16(af, b1, acc1, 0, 0, 0);
    }
#pragma unroll
    for (int r = 0; r < 4; ++r) {
        float bv = bias[otile + lhi * 4 + r];
        float* yr = Y + ((size_t)(b * OC + otile + lhi * 4 + r)) * N + ntile + l15;
        yr[0]  = acc0[r] + bv;
        yr[16] = acc1[r] + bv;
    }
}

// ---------------- K1: MFMA conv for q: fp32 [b][c][n] + fp16 SCALED [b][n][c] ----------------
__global__ __launch_bounds__(256)
void convq_mfma(const __half* __restrict__ Wh, const float* __restrict__ bias,
                const __half* __restrict__ XT, float* __restrict__ Y,
                __half* __restrict__ Qh)
{
    const int tid = threadIdx.x;
    const int wv = tid >> 6;
    const int lane = tid & 63;
    const int l15 = lane & 15, lhi = lane >> 4;
    const int otile = blockIdx.y * 64 + wv * 16;
    const int ntile = blockIdx.x * 32;
    const int b = blockIdx.z;

    const __half* Wp = Wh + (size_t)(otile + l15) * CC_ + lhi * 8;
    const __half* Xp0 = XT + ((size_t)(b * HWSZ + ntile + l15)) * CC_ + lhi * 8;
    const __half* Xp1 = Xp0 + (size_t)16 * CC_;

    f32x4_t acc0 = {0.f, 0.f, 0.f, 0.f}, acc1 = {0.f, 0.f, 0.f, 0.f};
#pragma unroll
    for (int k0 = 0; k0 < CC_; k0 += 32) {
        half8_t af = *(const half8_t*)(Wp + k0);
        half8_t b0 = *(const half8_t*)(Xp0 + k0);
        half8_t b1 = *(const half8_t*)(Xp1 + k0);
        acc0 = __builtin_amdgcn_mfma_f32_16x16x32_f16(af, b0, acc0, 0, 0, 0);
        acc1 = __builtin_amdgcn_mfma_f32_16x16x32_f16(af, b1, acc1, 0, 0, 0);
    }
    float bv[4];
#pragma unroll
    for (int r = 0; r < 4; ++r) bv[r] = bias[otile + lhi * 4 + r];
#pragma unroll
    for (int r = 0; r < 4; ++r) {
        float* yr = Y + ((size_t)(b * CC_ + otile + lhi * 4 + r)) * HWSZ + ntile + l15;
        yr[0]  = acc0[r] + bv[r];
        yr[16] = acc1[r] + bv[r];
    }
    {
        int n0 = ntile + l15;
        __half2 h0 = __floats2half2_rn((acc0[0] + bv[0]) * SCALE_, (acc0[1] + bv[1]) * SCALE_);
        __half2 h1 = __floats2half2_rn((acc0[2] + bv[2]) * SCALE_, (acc0[3] + bv[3]) * SCALE_);
        uint2 u;
        u.x = __builtin_bit_cast(unsigned, h0);
        u.y = __builtin_bit_cast(unsigned, h1);
        *(uint2*)(Qh + ((size_t)(b * HWSZ + n0)) * CC_ + otile + lhi * 4) = u;
        h0 = __floats2half2_rn((acc1[0] + bv[0]) * SCALE_, (acc1[1] + bv[1]) * SCALE_);
        h1 = __floats2half2_rn((acc1[2] + bv[2]) * SCALE_, (acc1[3] + bv[3]) * SCALE_);
        u.x = __builtin_bit_cast(unsigned, h0);
        u.y = __builtin_bit_cast(unsigned, h1);
        *(uint2*)(Qh + ((size_t)(b * HWSZ + n0 + 16)) * CC_ + otile + lhi * 4) = u;
    }
}

// ---------------- K4: MFMA fused K+V conv; K fp16 [bh][s][32], V fp16 [bh][c][s] ----------------
template<int CIN>
__global__ __launch_bounds__(256)
void convkv_mfma(const __half* __restrict__ Wkh, const float* __restrict__ bk,
                 const __half* __restrict__ Wvh, const float* __restrict__ bv,
                 const __half* __restrict__ XS, __half* __restrict__ Yk,
                 __half* __restrict__ Yv)
{
    const int tid = threadIdx.x;
    const int wv = tid >> 6;
    const int lane = tid & 63;
    const int l15 = lane & 15, lhi = lane >> 4;
    const int otile = blockIdx.y * 64 + wv * 16;
    const int stile = blockIdx.x * 32;
    const int b = blockIdx.z;

    const __half* Wkp = Wkh + (size_t)(otile + l15) * CIN + lhi * 8;
    const __half* Wvp = Wvh + (size_t)(otile + l15) * CIN + lhi * 8;
    const __half* Xp0 = XS + ((size_t)(b * NS_ + stile + l15)) * CIN + lhi * 8;
    const __half* Xp1 = Xp0 + (size_t)16 * CIN;

    f32x4_t ka0 = {0.f,0.f,0.f,0.f}, ka1 = {0.f,0.f,0.f,0.f};
    f32x4_t va0 = {0.f,0.f,0.f,0.f}, va1 = {0.f,0.f,0.f,0.f};
#pragma unroll
    for (int c0 = 0; c0 < CIN; c0 += 32) {
        half8_t ak = *(const half8_t*)(Wkp + c0);
        half8_t av = *(const half8_t*)(Wvp + c0);
        half8_t b0 = *(const half8_t*)(Xp0 + c0);
        half8_t b1 = *(const half8_t*)(Xp1 + c0);
        ka0 = __builtin_amdgcn_mfma_f32_16x16x32_f16(ak, b0, ka0, 0, 0, 0);
        ka1 = __builtin_amdgcn_mfma_f32_16x16x32_f16(ak, b1, ka1, 0, 0, 0);
        va0 = __builtin_amdgcn_mfma_f32_16x16x32_f16(av, b0, va0, 0, 0, 0);
        va1 = __builtin_amdgcn_mfma_f32_16x16x32_f16(av, b1, va1, 0, 0, 0);
    }
    const int h = otile >> 5;
    const int c32 = (otile & 31) + lhi * 4;
    const size_t bh = (size_t)(b * NHD + h);
    float bkv[4], bvv[4];
#pragma unroll
    for (int r = 0; r < 4; ++r) {
        bkv[r] = bk[otile + lhi * 4 + r];
        bvv[r] = bv[otile + lhi * 4 + r];
    }
    {
        size_t base = (bh * NS_ + stile + l15) * 32 + c32;
        __half2 kh[2];
        kh[0] = __floats2half2_rn(ka0[0] + bkv[0], ka0[1] + bkv[1]);
        kh[1] = __floats2half2_rn(ka0[2] + bkv[2], ka0[3] + bkv[3]);
        *(uint2*)(Yk + base) = *(uint2*)kh;
        base = (bh * NS_ + stile + 16 + l15) * 32 + c32;
        kh[0] = __floats2half2_rn(ka1[0] + bkv[0], ka1[1] + bkv[1]);
        kh[1] = __floats2half2_rn(ka1[2] + bkv[2], ka1[3] + bkv[3]);
        *(uint2*)(Yk + base) = *(uint2*)kh;
    }
    {
        __half* vdst = Yv + (bh * 32 + c32) * NS_;
#pragma unroll
        for (int r = 0; r < 4; ++r) {
            vdst[(size_t)r * NS_ + stile + l15]      = __float2half(va0[r] + bvv[r]);
            vdst[(size_t)r * NS_ + stile + 16 + l15] = __float2half(va1[r] + bvv[r]);
        }
    }
}

// ---------------- K2a: depthwise conv 5x5 stride 2, transposed output [bg][pos][ch] ----------------
__global__ void offset_dw_kernel(const float* __restrict__ qb, const float* __restrict__ dww,
                                 const float* __restrict__ dwb, float* __restrict__ cobuf)
{
    __shared__ float img[HWSZ];
    const int c = blockIdx.x, bg = blockIdx.y;
    const int b = bg / GG, g = bg - b * GG;
    const int tid = threadIdx.x;
    const float* src = qb + ((size_t)(b * CC_ + g * NGC_ + c)) * HWSZ;
    ((float4*)img)[tid] = ((const float4*)src)[tid];
    __syncthreads();
    const int oy = tid >> 4, ox = tid & 15;
    float s = dwb[c];
    const float* wf = dww + c * 25;
    const int iy0 = oy * 2 - 2, ix0 = ox * 2 - 2;
#pragma unroll
    for (int ky = 0; ky < 5; ++ky) {
        int iy = iy0 + ky;
        if (iy < 0 || iy > 31) continue;
#pragma unroll
        for (int kx = 0; kx < 5; ++kx) {
            int ix = ix0 + kx;
            if (ix < 0 || ix > 31) continue;
            s = fmaf(img[iy * 32 + ix], wf[ky * 5 + kx], s);
        }
    }
    cobuf[((size_t)(bg * 256 + tid)) * NGC_ + c] = s;
}

// ---------------- K2b+K3 fused: LN+GELU+pw+tanh -> pos, bilinear sample of xh -> xsh ----------------
__global__ void offset_finsample_kernel(const float* __restrict__ cobuf, const float* __restrict__ lng,
                                        const float* __restrict__ lnb, const float* __restrict__ pww,
                                        const __half* __restrict__ xh, float* __restrict__ posb,
                                        __half* __restrict__ xsh)
{
    __shared__ float pos_s[8];
    const int lane = threadIdx.x & 63;
    const int wv = threadIdx.x >> 6;
    const int gpos = blockIdx.x * 4 + wv;
    const int bg = gpos >> 8, pos = gpos & 255;
    const int oy = (pos >> 4), ox = pos & 15;
    const int b = bg / GG, g = bg - b * GG;

    float v = cobuf[(size_t)gpos * NGC_ + lane];
    float s1 = v, s2 = v * v;
#pragma unroll
    for (int off = 32; off >= 1; off >>= 1) {
        s1 += __shfl_xor(s1, off);
        s2 += __shfl_xor(s2, off);
    }
    float mu = s1 * (1.f / 64.f);
    float var = s2 * (1.f / 64.f) - mu * mu;
    float rstd = rsqrtf(var + 1e-5f);
    float t = (v - mu) * rstd * lng[lane] + lnb[lane];
    float gv = 0.5f * t * (1.f + erff(t * 0.70710678118654752f));
    float o0 = pww[lane] * gv;
    float o1 = pww[64 + lane] * gv;
#pragma unroll
    for (int off = 32; off >= 1; off >>= 1) {
        o0 += __shfl_xor(o0, off);
        o1 += __shfl_xor(o1, off);
    }
    if (lane == 0) {
        float py = tanhf(o0) * (2.f / 15.f) + ((0.5f + (float)oy) * (1.f / 15.f)) * 2.f - 1.f;
        float px = tanhf(o1) * (2.f / 15.f) + ((0.5f + (float)ox) * (1.f / 15.f)) * 2.f - 1.f;
        posb[bg * 512 + pos * 2 + 0] = py;
        posb[bg * 512 + pos * 2 + 1] = px;
        pos_s[wv * 2 + 0] = py;
        pos_s[wv * 2 + 1] = px;
    }
    __syncthreads();

    float py = pos_s[wv * 2 + 0], px = pos_s[wv * 2 + 1];
    float xi = (px + 1.f) * 0.5f * 31.f;
    float yi = (py + 1.f) * 0.5f * 31.f;
    float x0f = floorf(xi), y0f = floorf(yi);
    int x0 = (int)x0f, y0 = (int)y0f;
    float wx1 = xi - x0f, wy1 = yi - y0f;
    const __half* imgc = xh + (size_t)(b * HWSZ) * CC_ + g * NGC_ + lane;
    float acc = 0.f;
#pragma unroll
    for (int tt = 0; tt < 4; ++tt) {
        int iy = y0 + (tt >> 1), ix = x0 + (tt & 1);
        float w = ((tt >> 1) ? wy1 : 1.f - wy1) * ((tt & 1) ? wx1 : 1.f - wx1);
        if (iy >= 0 && iy <= 31 && ix >= 0 && ix <= 31)
            acc = fmaf(__half2float(imgc[(size_t)(iy * 32 + ix) * CC_]), w, acc);
    }
    xsh[((size_t)(b * NS_ + pos)) * CC_ + g * NGC_ + lane] = __float2half(acc);
}

// ---------------- K5: full-MFMA attention, 8 waves / 128 q per block ----------------
__launch_bounds__(512)
__global__ void attn_mfma(const __half* __restrict__ qh, const __half* __restrict__ kt,
                          const __half* __restrict__ vt, const float* __restrict__ posb,
                          const float* __restrict__ rpe, __half* __restrict__ aoT)
{
    __shared__ __half rph[4096];
    __shared__ float4 ytab[1024];
    const int bh = blockIdx.y;
    const int b = bh / NHD, h = bh - b * NHD;
    const int bg = b * GG + (h >> 1);
    const int tid = threadIdx.x;
    for (int e = tid; e < RPEW * RPEW; e += 512)
        rph[e] = __float2half(rpe[(size_t)h * (RPEW * RPEW) + e]);
    const int base_row = blockIdx.x * 4;
    for (int e = tid; e < 1024; e += 512) {
        int rr = e >> 8, s = e & 255;
        float py = posb[bg * 512 + s * 2 + 0];
        float px = posb[bg * 512 + s * 2 + 1];
        float ycr = ((float)(base_row + rr) * (2.f / 31.f) - 1.f) * 15.5f + 31.f;
        float yi = fmaf(py, -15.5f, ycr);
        float y0f = floorf(yi);
        int iy = (int)y0f;
        float wy1 = yi - y0f, wy0 = 1.f - wy1;
        if ((unsigned)iy > 62u)       wy0 = 0.f;
        if ((unsigned)(iy + 1) > 62u) wy1 = 0.f;
        int ry0 = min(max(iy, 0), 62) * 63;
        int ry1 = min(max(iy + 1, 0), 62) * 63;
        float4 t;
        t.x = __int_as_float(ry0);
        t.y = __int_as_float(ry1);
        t.z = __uint_as_float(__builtin_bit_cast(unsigned, __floats2half2_rn(wy0, wy1)));
        t.w = px * 15.5f;
        ytab[rr * 256 + s] = t;
    }
    __syncthreads();

    const int wave = tid >> 6;
    const int lane = tid & 63;
    const int l15 = lane & 15, lhi = lane >> 4;
    const int qglob = blockIdx.x * 128 + wave * 16 + l15;
    const int col = qglob & 31;
    const float xc = ((float)col * (2.f / 31.f) - 1.f) * 15.5f + 31.f;
    const int rowl = wave >> 1;

    half8_t qf = *(const half8_t*)(qh + ((size_t)(b * HWSZ + qglob)) * CC_ + h * HCH + lhi * 8);

    const __half* kbase = kt + (size_t)bh * NS_ * 32;
    const __half* vbase = vt + (size_t)bh * 32 * NS_;

    f32x4_t oacc0 = {0.f,0.f,0.f,0.f}, oacc1 = {0.f,0.f,0.f,0.f};
    const f32x4_t zero4 = {0.f,0.f,0.f,0.f};
    float lsum = 0.f;

    for (int chunk = 0; chunk < 8; ++chunk) {
        const int sbase = chunk * 32;
        unsigned wa0 = 0, wa1 = 0, wb0 = 0, wb1 = 0;
#pragma unroll
        for (int t = 0; t < 2; ++t) {
            const int stile = sbase + t * 16;
            half8_t kf = *(const half8_t*)(kbase + (size_t)(stile + l15) * 32 + lhi * 8);
            f32x4_t sf = __builtin_amdgcn_mfma_f32_16x16x32_f16(kf, qf, zero4, 0, 0, 0);
            float pv[4];
#pragma unroll
            for (int r = 0; r < 4; ++r) {
                const int s = stile + lhi * 4 + r;
                float4 yt = ytab[rowl * 256 + s];
                int ry0 = __float_as_int(yt.x), ry1 = __float_as_int(yt.y);
                __half2 wyh = __builtin_bit_cast(__half2, __float_as_uint(yt.z));
                float wy0 = __low2float(wyh), wy1 = __high2float(wyh);
                float xi = xc - yt.w;
                float x0f = floorf(xi);
                int ix = (int)x0f;
                float wx1 = xi - x0f, wx0 = 1.f - wx1;
                if ((unsigned)ix > 62u)       wx0 = 0.f;
                if ((unsigned)(ix + 1) > 62u) wx1 = 0.f;
                int cx0 = min(max(ix, 0), 62);
                int cx1 = min(max(ix + 1, 0), 62);
                float t00 = __half2float(rph[ry0 + cx0]), t01 = __half2float(rph[ry0 + cx1]);
                float t10 = __half2float(rph[ry1 + cx0]), t11 = __half2float(rph[ry1 + cx1]);
                float bias = wy0 * fmaf(wx0, t00, wx1 * t01)
                           + wy1 * fmaf(wx0, t10, wx1 * t11);
                float p = __expf(sf[r] + bias);
                lsum += p;
                pv[r] = p;
            }
            unsigned w0 = __builtin_bit_cast(unsigned, __floats2half2_rn(pv[0], pv[1]));
            unsigned w1 = __builtin_bit_cast(unsigned, __floats2half2_rn(pv[2], pv[3]));
            if (t == 0) { wa0 = w0; wa1 = w1; } else { wb0 = w0; wb1 = w1; }
        }
        const int srcA = l15 + ((lhi & 1) << 5);
        const int srcB = srcA + 16;
        int g0a = __shfl((int)wa0, srcA), g0b = __shfl((int)wb0, srcA);
        int g1a = __shfl((int)wa1, srcA), g1b = __shfl((int)wb1, srcA);
        int g2a = __shfl((int)wa0, srcB), g2b = __shfl((int)wb0, srcB);
        int g3a = __shfl((int)wa1, srcB), g3b = __shfl((int)wb1, srcB);
        const bool hi = (lhi >= 2);
        u32x4_t bw;
        bw[0] = (unsigned)(hi ? g0b : g0a);
        bw[1] = (unsigned)(hi ? g1b : g1a);
        bw[2] = (unsigned)(hi ? g2b : g2a);
        bw[3] = (unsigned)(hi ? g3b : g3a);
        half8_t pf = __builtin_bit_cast(half8_t, bw);
        half8_t vf0 = *(const half8_t*)(vbase + (size_t)(l15) * NS_ + sbase + lhi * 8);
        half8_t vf1 = *(const half8_t*)(vbase + (size_t)(16 + l15) * NS_ + sbase + lhi * 8);
        oacc0 = __builtin_amdgcn_mfma_f32_16x16x32_f16(vf0, pf, oacc0, 0, 0, 0);
        oacc1 = __builtin_amdgcn_mfma_f32_16x16x32_f16(vf1, pf, oacc1, 0, 0, 0);
    }
    lsum += __shfl_xor(lsum, 16);
    lsum += __shfl_xor(lsum, 32);
    const float inv = 1.f / lsum;
    __half* og = aoT + ((size_t)(b * HWSZ + qglob)) * CC_ + h * HCH;
    {
        __half2 h0 = __floats2half2_rn(oacc0[0] * inv, oacc0[1] * inv);
        __half2 h1 = __floats2half2_rn(oacc0[2] * inv, oacc0[3] * inv);
        uint2 u;
        u.x = __builtin_bit_cast(unsigned, h0);
        u.y = __builtin_bit_cast(unsigned, h1);
        *(uint2*)(og + lhi * 4) = u;
        h0 = __floats2half2_rn(oacc1[0] * inv, oacc1[1] * inv);
        h1 = __floats2half2_rn(oacc1[2] * inv, oacc1[3] * inv);
        u.x = __builtin_bit_cast(unsigned, h0);
        u.y = __builtin_bit_cast(unsigned, h1);
        *(uint2*)(og + 16 + lhi * 4) = u;
    }
}

extern "C" void kernel_launch(void* const* d_in, const int* in_sizes, int n_in,
                              void* d_out, int out_size, void* d_ws, size_t ws_size,
                              hipStream_t stream) {
    (void)in_sizes; (void)n_in; (void)out_size; (void)ws_size;
    const float* x   = (const float*)d_in[0];
    const float* Wq  = (const float*)d_in[1];
    const float* bq  = (const float*)d_in[2];
    const float* Wk  = (const float*)d_in[3];
    const float* bk  = (const float*)d_in[4];
    const float* Wv  = (const float*)d_in[5];
    const float* bv  = (const float*)d_in[6];
    const float* Wo  = (const float*)d_in[7];
    const float* bo  = (const float*)d_in[8];
    const float* dww = (const float*)d_in[9];
    const float* dwb = (const float*)d_in[10];
    const float* lng = (const float*)d_in[11];
    const float* lnb = (const float*)d_in[12];
    const float* pww = (const float*)d_in[13];
    const float* rpe = (const float*)d_in[14];
    float* out = (float*)d_out;

    // Workspace (float slots). Aliasing audited (R20-validated layout):
    //  cobuf aliases ktb+vth (dw -> finsample -> convkv overwrite, ordering-safe)
    //  qh == aoT alias (attn reads/writes same per-block region)
    float* p = (float*)d_ws;
    float* qbuf  = p; p += 1572864;                 // fp32 [b][c][n]
    float* posb  = p; p += 12288;
    __half* ktb  = (__half*)p; p += 196608;         // K fp16 [bh][s][32]
    __half* vth  = (__half*)p; p += 196608;         // V fp16 [bh][c][s]
    float* cobuf = (float*)ktb;
    __half* xh   = (__half*)p; p += 786432;         // fp16 [b][n][c]
    __half* qh   = (__half*)p; p += 786432;         // fp16 scaled [b][n][c]
    __half* aoT  = qh;
    __half* wqh  = (__half*)p; p += 73728;
    __half* woh  = (__half*)p; p += 73728;
    __half* wkh  = (__half*)p; p += 73728;
    __half* wvh  = (__half*)p; p += 73728;
    __half* xsh  = (__half*)p; p += 196608;         // fp16 [b][s][c]

    prep_kernel<<<dim3(960), 256, 0, stream>>>(Wq, Wo, Wk, Wv, wqh, woh, wkh, wvh, x, xh);
    convq_mfma<<<dim3(HWSZ / 32, CC_ / 64, BB), 256, 0, stream>>>(wqh, bq, xh, qbuf, qh);
    offset_dw_kernel<<<dim3(NGC_, 24), 256, 0, stream>>>(qbuf, dww, dwb, cobuf);
    offset_finsample_kernel<<<dim3(1536), 256, 0, stream>>>(cobuf, lng, lnb, pww, xh, posb, xsh);
    convkv_mfma<CC_><<<dim3(NS_ / 32, CC_ / 64, BB), 256, 0, stream>>>(wkh, bk, wvh, bv, xsh, ktb, vth);
    attn_mfma<<<dim3(8, BB * NHD), 512, 0, stream>>>(qh, ktb, vth, posb, rpe, aoT);
    conv1x1_mfma_h<CC_><<<dim3(HWSZ / 32, CC_ / 64, BB), 256, 0, stream>>>(woh, bo, aoT, out, HWSZ, CC_);
}